// Round 15
// baseline (1189.592 us; speedup 1.0000x reference)
//
#include <hip/hip_runtime.h>
#include <cstdint>

// ---------------- problem constants ----------------
#define NYD   256
#define NXD   256
#define PADC  22            // PML + FD_PAD
#define NYP_  300           // NY + 2*PAD
#define NXP_  300
#define NTT   250
#define NSHOT_ 2
#define NSRC_  8
#define NREC_  64
#define DT_   0.0005f

// guarded-array geometry
#define GDN   28
#define STP   356           // NXP_ + 2*GDN (multiple of 4 -> float4 alignment holds)
#define FP    (STP*STP)     // per-shot field words

// fused tile geometry: 8x32 output tile, T=2 steps/launch (r6-verified)
#define BY    8
#define BX    32
#define NTX   10            // ceil(300/32)
#define NTY   38            // ceil(300/8)
#define TPS   380           // tiles per shot
#define NWG   760           // = 8 XCDs * 95 -> perfect bijective swizzle

// ---------------- zero workspace ----------------
__global__ void zero_kernel(float* __restrict__ p, long n) {
    long i = (long)blockIdx.x * blockDim.x + threadIdx.x;
    long stride = (long)gridDim.x * blockDim.x;
    for (; i < n; i += stride) p[i] = 0.0f;
}

// ---------------- setup: v2dt2, PML profiles, receiver tile bins ----------------
__global__ void populate_kernel(const float* __restrict__ v,
                                const int* __restrict__ recloc,
                                float* __restrict__ v2dt2,   // [FP], guard stays 0
                                float* __restrict__ prof,    // [2*STP]: a, b (guard 0)
                                unsigned long long* __restrict__ recbin) { // [2][TPS]
    int i = blockIdx.x * 256 + threadIdx.x;

    if (i < NYP_ * NXP_) {
        int y = i / NXP_, x = i % NXP_;
        int vy = min(max(y - PADC, 0), NYD - 1);
        int vx = min(max(x - PADC, 0), NXD - 1);
        float vv = v[vy * NXD + vx];
        v2dt2[(y + GDN) * STP + (x + GDN)] = vv * vv * (DT_ * DT_);
    }

    if (i < NYP_) {  // DY == DX and NYP == NXP: one profile pair serves both axes
        float fi = (float)i;
        float d = fmaxf(22.0f - fi, fi - 277.0f);
        float frac = fminf(fmaxf(d * (1.0f / 20.0f), 0.0f), 1.0f);
        float sigma_max = 3.0f * 4000.0f * logf(1000.0f) / (2.0f * 20.0f * 5.0f);
        float sigma = sigma_max * frac * frac;
        float alpha = 3.14159265358979323846f * 25.0f * (1.0f - frac);
        float b = expf(-(sigma + alpha) * DT_);
        float a = sigma / (sigma + alpha + 1e-9f) * (b - 1.0f);
        prof[GDN + i] = a;
        prof[STP + GDN + i] = b;
    }

    if (i < NSHOT_ * NREC_) {
        int ry = recloc[2 * i] + PADC;
        int rx = recloc[2 * i + 1] + PADC;
        int shot = i / NREC_;
        int tl = (ry / BY) * NTX + (rx / BX);
        atomicOr(&recbin[shot * TPS + tl], 1ull << (i % NREC_));
    }
}

// ---------------- fused kernel: 2 steps/launch, 8x32 tiles, PML-sparse ----------------
// Structure byte-identical to the r6-verified fused kernel; adds PML sparsity
// (r14-validated): a(i)=0 for i in [22,277] => psiy/zetay are EXACTLY 0 for
// all rows in [22,277], psix/zetax for all cols in [22,277] (induction from
// zero init). Fused spans: psiy rows [ty0-6, ty0+14) -> ypml = ty0<=27 ||
// ty0>=265 (8/38 rows); psix cols [tx0-8, tx0+40) -> xpml = tx0<=29 ||
// tx0>=239 i.e. tx0 in {0,256,288} (3/10). Interior tiles skip psi/zeta
// staging, both psi phases, and psi/zeta stores (targets provably hold 0).
// Guards are per-block uniform; barriers stay top-level. Active-path math is
// expression-identical to r6 -> results bit-identical.
__global__ __launch_bounds__(256) void fused2_kernel(
    const float* __restrict__ wfm_g,   // wf(t-1)
    const float* __restrict__ wfc_g,   // wf(t)
    float* __restrict__ w1_g,          // out: wf(t+1)
    float* __restrict__ w2_g,          // out: wf(t+2)
    const float* __restrict__ pyr_g, float* __restrict__ pyw_g,
    const float* __restrict__ pxr_g, float* __restrict__ pxw_g,
    const float* __restrict__ zyr_g, float* __restrict__ zyw_g,
    const float* __restrict__ zxr_g, float* __restrict__ zxw_g,
    const float* __restrict__ v2_g, const float* __restrict__ prof,
    const unsigned long long* __restrict__ recbin,
    const int* __restrict__ srcloc, const int* __restrict__ recloc,
    const float* __restrict__ amps,   // [NSHOT][NSRC][NT]
    float* __restrict__ out,          // [NSHOT][NREC][NT]
    int t) {
    // bijective XCD swizzle: NWG = 760 = 8 * 95
    const int orig = blockIdx.x;
    const int wgid = (orig & 7) * 95 + (orig >> 3);
    const int shot = wgid / TPS;
    const int tl   = wgid - shot * TPS;
    const int ty0  = (tl / NTX) * BY;
    const int tx0  = (tl % NTX) * BX;

    // PML classification (per-block uniform; fused spans)
    const bool ypml = (ty0 <= 27) || (ty0 >= 265);
    const bool xpml = (tx0 <= 29) || (tx0 >= 239);

    const float* wfm = wfm_g + shot * FP;
    const float* wfc = wfc_g + shot * FP;
    float*       w1o = w1_g  + shot * FP;
    float*       w2o = w2_g  + shot * FP;
    const float* pyr = pyr_g + shot * FP;
    float*       pyw = pyw_g + shot * FP;
    const float* pxr = pxr_g + shot * FP;
    float*       pxw = pxw_g + shot * FP;
    const float* zyr = zyr_g + shot * FP;
    float*       zyw = zyw_g + shot * FP;
    const float* zxr = zxr_g + shot * FP;
    float*       zxw = zxw_g + shot * FP;

    __shared__ float swf0[24][48];
    __shared__ float spy [20][40];
    __shared__ float spx [16][48];
    __shared__ float swf1[16][40];
    __shared__ float szy [16][40];
    __shared__ float szx [16][40];
    __shared__ float sv2 [16][40];
    __shared__ float swm [16][40];
    __shared__ float sya[24], syb[24], sxa[48], sxb[48];
    __shared__ int   ssy[NSRC_], ssx[NSRC_], sry[NREC_], srx[NREC_];
    __shared__ unsigned long long srb;

    const int tid = threadIdx.x;

    // ---- stage (conditional segments; all loads independent) ----
#pragma unroll
    for (int li = 0; li < 6; li++) {
        int lin = tid + li * 256;
        if (lin < 288) {                     // swf0: 24 x 12 f4 from (ty0-8, tx0-8) [always]
            int rr = lin / 12, cc = lin % 12;
            *reinterpret_cast<float4*>(&swf0[rr][cc * 4]) =
                *reinterpret_cast<const float4*>(wfc + (ty0 - 8 + rr + GDN) * STP + (tx0 - 8 + GDN) + cc * 4);
        } else if (lin < 488) {              // spy: 20 x 10 f4 from (ty0-6, tx0-4) [ypml]
            if (ypml) {
                int l = lin - 288; int rr = l / 10, cc = l % 10;
                *reinterpret_cast<float4*>(&spy[rr][cc * 4]) =
                    *reinterpret_cast<const float4*>(pyr + (ty0 - 6 + rr + GDN) * STP + (tx0 - 4 + GDN) + cc * 4);
            }
        } else if (lin < 680) {              // spx: 16 x 12 f4 from (ty0-4, tx0-8) [xpml]
            if (xpml) {
                int l = lin - 488; int rr = l / 12, cc = l % 12;
                *reinterpret_cast<float4*>(&spx[rr][cc * 4]) =
                    *reinterpret_cast<const float4*>(pxr + (ty0 - 4 + rr + GDN) * STP + (tx0 - 8 + GDN) + cc * 4);
            }
        } else if (lin < 840) {              // szy: 16 x 10 f4 from (ty0-4, tx0-4) [ypml]
            if (ypml) {
                int l = lin - 680; int rr = l / 10, cc = l % 10;
                *reinterpret_cast<float4*>(&szy[rr][cc * 4]) =
                    *reinterpret_cast<const float4*>(zyr + (ty0 - 4 + rr + GDN) * STP + (tx0 - 4 + GDN) + cc * 4);
            }
        } else if (lin < 1000) {             // szx [xpml]
            if (xpml) {
                int l = lin - 840; int rr = l / 10, cc = l % 10;
                *reinterpret_cast<float4*>(&szx[rr][cc * 4]) =
                    *reinterpret_cast<const float4*>(zxr + (ty0 - 4 + rr + GDN) * STP + (tx0 - 4 + GDN) + cc * 4);
            }
        } else if (lin < 1160) {             // sv2 [always]
            int l = lin - 1000; int rr = l / 10, cc = l % 10;
            *reinterpret_cast<float4*>(&sv2[rr][cc * 4]) =
                *reinterpret_cast<const float4*>(v2_g + (ty0 - 4 + rr + GDN) * STP + (tx0 - 4 + GDN) + cc * 4);
        } else if (lin < 1320) {             // swm = wf(t-1) on W1 [always]
            int l = lin - 1160; int rr = l / 10, cc = l % 10;
            *reinterpret_cast<float4*>(&swm[rr][cc * 4]) =
                *reinterpret_cast<const float4*>(wfm + (ty0 - 4 + rr + GDN) * STP + (tx0 - 4 + GDN) + cc * 4);
        }
    }
    if (tid < 24) {
        sya[tid] = prof[GDN + ty0 - 8 + tid];
        syb[tid] = prof[STP + GDN + ty0 - 8 + tid];
    }
    if (tid < 48) {
        sxa[tid] = prof[GDN + tx0 - 8 + tid];
        sxb[tid] = prof[STP + GDN + tx0 - 8 + tid];
    }
    if (tid < NSRC_) {
        ssy[tid] = srcloc[(shot * NSRC_ + tid) * 2]     + PADC;
        ssx[tid] = srcloc[(shot * NSRC_ + tid) * 2 + 1] + PADC;
    }
    if (tid < NREC_) {
        sry[tid] = recloc[(shot * NREC_ + tid) * 2]     + PADC;
        srx[tid] = recloc[(shot * NREC_ + tid) * 2 + 1] + PADC;
    }
    if (tid == 0) srb = recbin[shot * TPS + tl];
    __syncthreads();

    const float ih  = 0.2f;    // 1/DY
    const float ih2 = 0.04f;   // 1/DY^2
    const float C1A = 2.0f / 3.0f, C1B = 1.0f / 12.0f;
    const float C2A = 4.0f / 3.0f, C2B = -1.0f / 12.0f, C2C = -2.5f;

    // ---- psi(t) -> psi(t+1), in place (guarded) ----
#pragma unroll
    for (int li = 0; li < 6; li++) {
        int lin = tid + li * 256;
        if (lin < 800) {                       // spy cell (r,c): y=ty0-6+r, x=tx0-4+c
            if (ypml) {
                int r = lin / 40, c = lin % 40;
                float dw = (C1A * (swf0[r + 3][c + 4] - swf0[r + 1][c + 4])
                          - C1B * (swf0[r + 4][c + 4] - swf0[r][c + 4])) * ih;
                spy[r][c] = syb[r + 2] * spy[r][c] + sya[r + 2] * dw;
            }
        } else if (lin < 1504) {               // spx cols 2..45: y=ty0-4+r, x=tx0-8+c
            if (xpml) {
                int l = lin - 800; int r = l / 44, c = l % 44 + 2;
                float dw = (C1A * (swf0[r + 4][c + 1] - swf0[r + 4][c - 1])
                          - C1B * (swf0[r + 4][c + 2] - swf0[r + 4][c - 2])) * ih;
                spx[r][c] = sxb[c] * spx[r][c] + sxa[c] * dw;
            }
        }
    }
    __syncthreads();

    // ---- wf(t+1) + zeta(t+1) on W1 (640 cells; psi terms guarded) ----
#pragma unroll
    for (int li = 0; li < 3; li++) {
        int lin = tid + li * 256;
        if (lin < 640) {
            int r = lin / 40, c = lin % 40;    // y=ty0-4+r, x=tx0-4+c
            float wc = swf0[r + 4][c + 4];
            float d2y = (C2B * (swf0[r + 2][c + 4] + swf0[r + 6][c + 4])
                       + C2A * (swf0[r + 3][c + 4] + swf0[r + 5][c + 4]) + C2C * wc) * ih2;
            float d2x = (C2B * (swf0[r + 4][c + 2] + swf0[r + 4][c + 6])
                       + C2A * (swf0[r + 4][c + 3] + swf0[r + 4][c + 5]) + C2C * wc) * ih2;
            float dpy = 0.0f, zy1 = 0.0f;
            if (ypml) {
                dpy = (C1A * (spy[r + 3][c] - spy[r + 1][c])
                     - C1B * (spy[r + 4][c] - spy[r][c])) * ih;
                zy1 = syb[r + 4] * szy[r][c] + sya[r + 4] * (d2y + dpy);
                szy[r][c] = zy1;
            }
            float dpx = 0.0f, zx1 = 0.0f;
            if (xpml) {
                dpx = (C1A * (spx[r][c + 5] - spx[r][c + 3])
                     - C1B * (spx[r][c + 6] - spx[r][c + 2])) * ih;
                zx1 = sxb[c + 4] * szx[r][c] + sxa[c + 4] * (d2x + dpx);
                szx[r][c] = zx1;
            }
            float vd = sv2[r][c];
            float w1 = 2.0f * wc - swm[r][c] + vd * (d2y + d2x + dpy + dpx + zy1 + zx1);
            int y = ty0 - 4 + r, x = tx0 - 4 + c;
#pragma unroll
            for (int q = 0; q < NSRC_; q++)
                if (ssy[q] == y && ssx[q] == x)
                    w1 += vd * amps[(shot * NSRC_ + q) * NTT + t];
            swf1[r][c] = w1;
        }
    }
    __syncthreads();

    // ---- psi(t+1) -> psi(t+2) on O+2, in place (guarded) ----
#pragma unroll
    for (int li = 0; li < 3; li++) {
        int lin = tid + li * 256;
        if (lin < 384) {                       // psiy(t+2): y=ty0-2+r, x=tx0+c
            if (ypml) {
                int r = lin / 32, c = lin % 32;
                float dw1 = (C1A * (swf1[r + 3][c + 4] - swf1[r + 1][c + 4])
                           - C1B * (swf1[r + 4][c + 4] - swf1[r][c + 4])) * ih;
                spy[r + 4][c + 4] = syb[r + 6] * spy[r + 4][c + 4] + sya[r + 6] * dw1;
            }
        } else if (lin < 672) {                // psix(t+2): y=ty0+r, x=tx0-2+c2
            if (xpml) {
                int l = lin - 384; int r = l / 36, c2 = l % 36;
                float dw1 = (C1A * (swf1[r + 4][c2 + 3] - swf1[r + 4][c2 + 1])
                           - C1B * (swf1[r + 4][c2 + 4] - swf1[r + 4][c2])) * ih;
                spx[r + 4][c2 + 6] = sxb[c2 + 6] * spx[r + 4][c2 + 6] + sxa[c2 + 6] * dw1;
            }
        }
    }
    __syncthreads();

    // ---- wf(t+2) + zeta(t+2) + writeback on O (1 cell/thread) ----
    {
        int ly = tid >> 5, lx = tid & 31;
        int y = ty0 + ly, x = tx0 + lx;
        float w1c = swf1[ly + 4][lx + 4];
        float d2y1 = (C2B * (swf1[ly + 2][lx + 4] + swf1[ly + 6][lx + 4])
                    + C2A * (swf1[ly + 3][lx + 4] + swf1[ly + 5][lx + 4]) + C2C * w1c) * ih2;
        float d2x1 = (C2B * (swf1[ly + 4][lx + 2] + swf1[ly + 4][lx + 6])
                    + C2A * (swf1[ly + 4][lx + 3] + swf1[ly + 4][lx + 5]) + C2C * w1c) * ih2;
        float dpy2 = 0.0f, zy2 = 0.0f;
        if (ypml) {
            dpy2 = (C1A * (spy[ly + 7][lx + 4] - spy[ly + 5][lx + 4])
                  - C1B * (spy[ly + 8][lx + 4] - spy[ly + 4][lx + 4])) * ih;
            zy2 = syb[ly + 8] * szy[ly + 4][lx + 4] + sya[ly + 8] * (d2y1 + dpy2);
        }
        float dpx2 = 0.0f, zx2 = 0.0f;
        if (xpml) {
            dpx2 = (C1A * (spx[ly + 4][lx + 9] - spx[ly + 4][lx + 7])
                  - C1B * (spx[ly + 4][lx + 10] - spx[ly + 4][lx + 6])) * ih;
            zx2 = sxb[lx + 8] * szx[ly + 4][lx + 4] + sxa[lx + 8] * (d2x1 + dpx2);
        }
        float vd = sv2[ly + 4][lx + 4];
        float w2 = 2.0f * w1c - swf0[ly + 8][lx + 8]
                 + vd * (d2y1 + d2x1 + dpy2 + dpx2 + zy2 + zx2);
#pragma unroll
        for (int q = 0; q < NSRC_; q++)
            if (ssy[q] == y && ssx[q] == x)
                w2 += vd * amps[(shot * NSRC_ + q) * NTT + t + 1];

        if (y < NYP_ && x < NXP_) {
            int g = (y + GDN) * STP + (x + GDN);
            w1o[g] = w1c;
            w2o[g] = w2;
            if (ypml) {
                pyw[g] = spy[ly + 6][lx + 4];   // interior: target already holds 0
                zyw[g] = zy2;
            }
            if (xpml) {
                pxw[g] = spx[ly + 4][lx + 8];
                zxw[g] = zx2;
            }
            unsigned long long rb = srb;
            while (rb) {
                int r = __ffsll(rb) - 1;
                rb &= rb - 1;
                if (sry[r] == y && srx[r] == x) {
                    out[(shot * NREC_ + r) * NTT + t]     = w1c;
                    out[(shot * NREC_ + r) * NTT + t + 1] = w2;
                }
            }
        }
    }
}

// ---------------- host ----------------
extern "C" void kernel_launch(void* const* d_in, const int* in_sizes, int n_in,
                              void* d_out, int out_size, void* d_ws, size_t ws_size,
                              hipStream_t stream) {
    const float* v      = (const float*)d_in[0];
    const float* amps   = (const float*)d_in[1];
    const int*   srcloc = (const int*)d_in[2];
    const int*   recloc = (const int*)d_in[3];
    float* out = (float*)d_out;

    float* base = (float*)d_ws;
    float* W0  = base;             // each: [2 shots][FP]
    float* W1  = W0  + 2L * FP;
    float* W2  = W1  + 2L * FP;
    float* W3  = W2  + 2L * FP;
    float* PY0 = W3  + 2L * FP;
    float* PY1 = PY0 + 2L * FP;
    float* PX0 = PY1 + 2L * FP;
    float* PX1 = PX0 + 2L * FP;
    float* ZY0 = PX1 + 2L * FP;
    float* ZY1 = ZY0 + 2L * FP;
    float* ZX0 = ZY1 + 2L * FP;
    float* ZX1 = ZX0 + 2L * FP;
    float* V2  = ZX1 + 2L * FP;    // [FP], shot-independent
    float* PROF = V2 + FP;         // [2*STP]
    unsigned long long* RECBIN = (unsigned long long*)(PROF + 2 * STP);  // [2][TPS]

    const long total_words = 25L * FP + 2 * STP + 2L * NSHOT_ * TPS;

    zero_kernel<<<2048, 256, 0, stream>>>(base, total_words);
    populate_kernel<<<(NYP_ * NXP_ + 255) / 256, 256, 0, stream>>>(
        v, recloc, V2, PROF, RECBIN);

    // 125 launches of 2 fused steps; wf buffers rotate (A,B,C,D)->(C,D,A,B)
    for (int k = 0; k < NTT / 2; k++) {
        const bool o = (k & 1);
        fused2_kernel<<<NWG, 256, 0, stream>>>(
            o ? W2 : W0, o ? W3 : W1,   // wf(t-1), wf(t)
            o ? W0 : W2, o ? W1 : W3,   // wf(t+1), wf(t+2)
            o ? PY1 : PY0, o ? PY0 : PY1,
            o ? PX1 : PX0, o ? PX0 : PX1,
            o ? ZY1 : ZY0, o ? ZY0 : ZY1,
            o ? ZX1 : ZX0, o ? ZX0 : ZX1,
            V2, PROF, RECBIN, srcloc, recloc, amps, out, 2 * k);
    }
}

// Round 18
// 1062.991 us; speedup vs baseline: 1.1191x; 1.1191x over previous
//
#include <hip/hip_runtime.h>
#include <cstdint>

// ---------------- problem constants ----------------
#define NYD   256
#define NXD   256
#define PADC  22            // PML + FD_PAD
#define NYP_  300           // NY + 2*PAD
#define NXP_  300
#define NTT   250
#define NSHOT_ 2
#define NSRC_  8
#define NREC_  64
#define DT_   0.0005f

// guarded-array geometry: guard 28 covers tile overhang (cols 300..319) + stencil halo
#define GDN   28
#define STP   356           // NXP_ + 2*GDN
#define FP    (STP*STP)     // per-shot field words (126736)

// tile geometry: 64x4 output tile, 256 threads, 1 cell/thread
#define NTX   5             // ceil(300/64)
#define NTY   75            // 300/4
#define TPS   375           // tiles per shot
#define NWG   750           // total blocks

// ---------------- zero workspace ----------------
__global__ void zero_kernel(float* __restrict__ p, long n) {
    long i = (long)blockIdx.x * blockDim.x + threadIdx.x;
    long stride = (long)gridDim.x * blockDim.x;
    for (; i < n; i += stride) p[i] = 0.0f;
}

// ---------------- setup: v2dt2, PML profiles, src/rec tile bins ----------------
__global__ void populate_kernel(const float* __restrict__ v,
                                const int* __restrict__ srcloc,
                                const int* __restrict__ recloc,
                                float* __restrict__ v2dt2,   // [FP], guard stays 0
                                float* __restrict__ prof,    // [2*STP]: a, b (guard 0)
                                unsigned* __restrict__ srcbin,            // [2][TPS]
                                unsigned long long* __restrict__ recbin) { // [2][TPS]
    int i = blockIdx.x * 256 + threadIdx.x;

    if (i < NYP_ * NXP_) {
        int y = i / NXP_, x = i % NXP_;
        int vy = min(max(y - PADC, 0), NYD - 1);
        int vx = min(max(x - PADC, 0), NXD - 1);
        float vv = v[vy * NXD + vx];
        v2dt2[(y + GDN) * STP + (x + GDN)] = vv * vv * (DT_ * DT_);
    }

    if (i < NYP_) {  // DY == DX and NYP == NXP: one profile pair serves both axes
        float fi = (float)i;
        float d = fmaxf(22.0f - fi, fi - 277.0f);
        float frac = fminf(fmaxf(d * (1.0f / 20.0f), 0.0f), 1.0f);
        float sigma_max = 3.0f * 4000.0f * logf(1000.0f) / (2.0f * 20.0f * 5.0f);
        float sigma = sigma_max * frac * frac;
        float alpha = 3.14159265358979323846f * 25.0f * (1.0f - frac);
        float b = expf(-(sigma + alpha) * DT_);
        float a = sigma / (sigma + alpha + 1e-9f) * (b - 1.0f);
        prof[GDN + i] = a;
        prof[STP + GDN + i] = b;
    }

    if (i < NSHOT_ * NSRC_) {
        int sy = srcloc[2 * i] + PADC;
        int sx = srcloc[2 * i + 1] + PADC;
        int shot = i / NSRC_;
        int tl = (sy / 4) * NTX + (sx / 64);
        atomicOr(&srcbin[shot * TPS + tl], 1u << (i % NSRC_));
    }

    if (i >= 1024 && i < 1024 + NSHOT_ * NREC_) {
        int j = i - 1024;
        int ry = recloc[2 * j] + PADC;
        int rx = recloc[2 * j + 1] + PADC;
        int shot = j / NREC_;
        int tl = (ry / 4) * NTX + (rx / 64);
        atomicOr(&recbin[shot * TPS + tl], 1ull << (j % NREC_));
    }
}

// ---------------- one time step, LDS-staged, PML-sparse ----------------
// r5/r13 structure (verified) + PML sparsity: a(i)=0 for i in [22,277], so
// psiy/zetay are EXACTLY 0 for all rows in [22,277] and psix/zetax for all
// cols in [22,277] (induction from zero init: psi_new = b*0 + 0*dw = 0; zeta
// likewise). A tile runs the y-PML path only if its psiy span [ty0-2, ty0+5]
// exits [22,277] -> ypml = ty0<24 || ty0>272 (12/75 rows); the x-PML path
// only if staged psix cols [tx0-4, tx0+67] exit the band -> xpml = tx0==0 ||
// tx0==256 (2/5 cols). Classifications are independent (a_x is a function of
// x only). Interior tiles skip psi staging, pn computation, and psi/zeta
// loads+stores (those locations provably hold 0). Branches are per-block
// uniform -> no divergence. Active-path math is expression-identical to the
// verified kernel. Measured r14: 1069 us (4.28 us/step).
__global__ __launch_bounds__(256) void step_kernel(
    const float* __restrict__ wfc_g,   // wf(t)   [2][FP]
    float* __restrict__ wfn_g,         // wf(t-1) in / wf(t+1) out
    const float* __restrict__ pyr_g, float* __restrict__ pyw_g,
    const float* __restrict__ pxr_g, float* __restrict__ pxw_g,
    float* __restrict__ zy_g, float* __restrict__ zx_g,
    const float* __restrict__ v2_g, const float* __restrict__ prof,
    const unsigned* __restrict__ srcbin,
    const unsigned long long* __restrict__ recbin,
    const int* __restrict__ srcloc, const int* __restrict__ recloc,
    const float* __restrict__ amps,   // [NSHOT][NSRC][NT]
    float* __restrict__ out,          // [NSHOT][NREC][NT]
    int t) {
    // bijective XCD swizzle: NWG=750, 8 XCDs, q=93, r=6
    int orig = blockIdx.x;
    int xcd = orig & 7, idx = orig >> 3;
    int wgid = (xcd < 6) ? xcd * 94 + idx : 6 * 94 + (xcd - 6) * 93 + idx;
    int shot = wgid / TPS;
    int tl   = wgid - shot * TPS;
    int ty0  = (tl / NTX) * 4;
    int tx0  = (tl % NTX) * 64;

    // PML classification (per-block uniform)
    const bool ypml = (ty0 < 24) || (ty0 > 272);
    const bool xpml = (tx0 == 0) || (tx0 == 256);

    const float* wfc = wfc_g + shot * FP;
    float*       wfn = wfn_g + shot * FP;
    const float* pyr = pyr_g + shot * FP;
    float*       pyw = pyw_g + shot * FP;
    const float* pxr = pxr_g + shot * FP;
    float*       pxw = pxw_g + shot * FP;
    float*       zyg = zy_g  + shot * FP;
    float*       zxg = zx_g  + shot * FP;

    __shared__ float swf[12][72];    // wf(t): rows ty0-4..ty0+7, cols tx0-4..tx0+67
    __shared__ float spy[8][64];     // psiy:  rows ty0-2..ty0+5, cols tx0..tx0+63
    __shared__ float spx[4][72];     // psix:  rows ty0..ty0+3,  cols tx0-4..tx0+67
    __shared__ float sya[8], syb[8], sxa[68], sxb[68];
    __shared__ int   ssy[NSRC_], ssx[NSRC_], sry[NREC_], srx[NREC_];
    __shared__ unsigned sbs;
    __shared__ unsigned long long sbr;

    const int tid = threadIdx.x;
    const int lx = tid & 63, ly = tid >> 6;
    const int y = ty0 + ly, x = tx0 + lx;
    const int g = (y + GDN) * STP + (x + GDN);

    // self-cell state (independent scalar loads, coalesced)
    float wm = wfn[g];
    float zy = ypml ? zyg[g] : 0.0f;   // provably 0 in interior
    float zx = xpml ? zxg[g] : 0.0f;
    float vd = v2_g[g];

    // staged loads (float4, all independent; psi staged only where nonzero)
    if (tid < 216) {                              // wf: 12 x 18 float4 (always)
        int rr = tid / 18, cc = tid % 18;
        const float4 val = *(reinterpret_cast<const float4*>(
            wfc + (ty0 - 4 + rr + GDN) * STP + (tx0 - 4 + GDN)) + cc);
        *reinterpret_cast<float4*>(&swf[rr][cc * 4]) = val;
    }
    if (ypml && tid < 128) {                      // psiy: 8 x 16 float4
        int rr = tid / 16, cc = tid % 16;
        const float4 val = *(reinterpret_cast<const float4*>(
            pyr + (ty0 - 2 + rr + GDN) * STP + (tx0 + GDN)) + cc);
        *reinterpret_cast<float4*>(&spy[rr][cc * 4]) = val;
    }
    if (xpml && tid < 72) {                       // psix: 4 x 18 float4
        int rr = tid / 18, cc = tid % 18;
        const float4 val = *(reinterpret_cast<const float4*>(
            pxr + (ty0 + rr + GDN) * STP + (tx0 - 4 + GDN)) + cc);
        *reinterpret_cast<float4*>(&spx[rr][cc * 4]) = val;
    }
    if (tid < 8) {
        sya[tid] = prof[GDN + ty0 - 2 + tid];
        syb[tid] = prof[STP + GDN + ty0 - 2 + tid];
        ssy[tid] = srcloc[(shot * NSRC_ + tid) * 2]     + PADC;
        ssx[tid] = srcloc[(shot * NSRC_ + tid) * 2 + 1] + PADC;
    }
    if (tid < 68) {
        sxa[tid] = prof[GDN + tx0 - 2 + tid];
        sxb[tid] = prof[STP + GDN + tx0 - 2 + tid];
    }
    if (tid < NREC_) {
        sry[tid] = recloc[(shot * NREC_ + tid) * 2]     + PADC;
        srx[tid] = recloc[(shot * NREC_ + tid) * 2 + 1] + PADC;
    }
    if (tid == 0) {
        sbs = srcbin[shot * TPS + tl];
        sbr = recbin[shot * TPS + tl];
    }
    __syncthreads();

    const float ih  = 0.2f;    // 1/DY
    const float ih2 = 0.04f;   // 1/DY^2
    const float C1A = 2.0f / 3.0f, C1B = 1.0f / 12.0f;
    const float C2A = 4.0f / 3.0f, C2B = -1.0f / 12.0f, C2C = -2.5f;

    float wy[9];
#pragma unroll
    for (int k = 0; k < 9; k++) wy[k] = swf[ly + k][lx + 4];
    float wx[9];
#pragma unroll
    for (int k = 0; k < 9; k++) wx[k] = (k == 4) ? wy[4] : swf[ly + 4][lx + k];

    float d2y = (C2B * (wy[2] + wy[6]) + C2A * (wy[3] + wy[5]) + C2C * wy[4]) * ih2;
    float d2x = (C2B * (wx[2] + wx[6]) + C2A * (wx[3] + wx[5]) + C2C * wx[4]) * ih2;

    // y-PML path (psiy/zetay nonzero only here)
    float dpsiy = 0.0f, pny2 = 0.0f;
    if (ypml) {
        float pny[5];
#pragma unroll
        for (int j = 0; j < 5; j++) {
            float dwdy = (C1A * (wy[j + 3] - wy[j + 1]) - C1B * (wy[j + 4] - wy[j])) * ih;
            pny[j] = syb[ly + j] * spy[ly + j][lx] + sya[ly + j] * dwdy;
        }
        dpsiy = (C1A * (pny[3] - pny[1]) - C1B * (pny[4] - pny[0])) * ih;
        pny2 = pny[2];
        float ay_ = sya[ly + 2], by_ = syb[ly + 2];
        zy = by_ * zy + ay_ * (d2y + dpsiy);
    }

    // x-PML path (psix/zetax nonzero only here)
    float dpsix = 0.0f, pnx2 = 0.0f;
    if (xpml) {
        float pnx[5];
#pragma unroll
        for (int j = 0; j < 5; j++) {
            float dwdx = (C1A * (wx[j + 3] - wx[j + 1]) - C1B * (wx[j + 4] - wx[j])) * ih;
            pnx[j] = sxb[lx + j] * spx[ly][lx + j + 2] + sxa[lx + j] * dwdx;
        }
        dpsix = (C1A * (pnx[3] - pnx[1]) - C1B * (pnx[4] - pnx[0])) * ih;
        pnx2 = pnx[2];
        float ax_ = sxa[lx + 2], bx_ = sxb[lx + 2];
        zx = bx_ * zx + ax_ * (d2x + dpsix);
    }

    float lap = d2y + d2x + dpsiy + dpsix + zy + zx;
    float wfp = 2.0f * wy[4] - wm + vd * lap;

    // source injection (matches reference order: before store & record)
    if (sbs) {
#pragma unroll
        for (int q = 0; q < NSRC_; q++)
            if ((sbs & (1u << q)) && ssy[q] == y && ssx[q] == x)
                wfp += vd * amps[(shot * NSRC_ + q) * NTT + t];
    }

    wfn[g] = wfp;
    if (ypml) {
        pyw[g] = pny2;     // interior: target already holds 0 == pny2
        zyg[g] = zy;
    }
    if (xpml) {
        pxw[g] = pnx2;
        zxg[g] = zx;
    }

    unsigned long long rb = sbr;
    while (rb) {
        int r = __ffsll(rb) - 1;
        rb &= rb - 1;
        if (sry[r] == y && srx[r] == x)
            out[(shot * NREC_ + r) * NTT + t] = wfp;
    }
}

// ---------------- host ----------------
extern "C" void kernel_launch(void* const* d_in, const int* in_sizes, int n_in,
                              void* d_out, int out_size, void* d_ws, size_t ws_size,
                              hipStream_t stream) {
    const float* v      = (const float*)d_in[0];
    const float* amps   = (const float*)d_in[1];
    const int*   srcloc = (const int*)d_in[2];
    const int*   recloc = (const int*)d_in[3];
    float* out = (float*)d_out;

    float* base = (float*)d_ws;
    float* WF0 = base;             // each: [2 shots][FP]
    float* WF1 = WF0 + 2L * FP;
    float* PY0 = WF1 + 2L * FP;
    float* PY1 = PY0 + 2L * FP;
    float* PX0 = PY1 + 2L * FP;
    float* PX1 = PX0 + 2L * FP;
    float* ZY  = PX1 + 2L * FP;    // in-place (self-cell)
    float* ZX  = ZY  + 2L * FP;
    float* V2  = ZX  + 2L * FP;    // [FP], shot-independent
    float* PROF = V2 + FP;         // [2*STP]
    unsigned* SRCBIN = (unsigned*)(PROF + 2 * STP);                 // 750 words
    unsigned long long* RECBIN = (unsigned long long*)(SRCBIN + NSHOT_ * TPS);  // 1500 words

    const long total_words = 17L * FP + 2 * STP + NSHOT_ * TPS + 2L * NSHOT_ * TPS;

    zero_kernel<<<2048, 256, 0, stream>>>(base, total_words);
    populate_kernel<<<(NYP_ * NXP_ + 255) / 256, 256, 0, stream>>>(
        v, srcloc, recloc, V2, PROF, SRCBIN, RECBIN);

    for (int t = 0; t < NTT; t++) {
        const bool o = (t & 1);
        step_kernel<<<NWG, 256, 0, stream>>>(
            o ? WF1 : WF0, o ? WF0 : WF1,
            o ? PY1 : PY0, o ? PY0 : PY1,
            o ? PX1 : PX0, o ? PX0 : PX1,
            ZY, ZX, V2, PROF, SRCBIN, RECBIN,
            srcloc, recloc, amps, out, t);
    }
}